// Round 5
// baseline (13683.817 us; speedup 1.0000x reference)
//
#include <hip/hip_runtime.h>
#include <math.h>

// LSTM_360 R5: dispatch-per-step; stage A restructured for latency hiding.
// 256 blocks x 512 threads (8 waves = 2 waves/SIMD on all 256 CUs).
//  Stage A (all blocks): gates GEMM (M=128,N=4096,K=1280). Block tile 64x32,
//    waves = wm(2) x wk(4 K-quarters); partial sums combined via 4 LDS regions.
//  Stage B (blocks 0..15, after A): logits_{t-1} = h_{t-1} @ Wout^T + bout.
//  Stage C (blocks 16..31, after A): log_softmax(logits_{t-2}) -> out,
//    one row per wave, shuffle-only.
// Weight layout Wc[n][k], n = j*4+gate (block's 32-col slice = 8 hidden units).

#define TT  512
#define BB  128
#define NIN 256
#define NH  1024
#define G4  4096
#define KK  1280

typedef __bf16 bf16_t;
typedef bf16_t bf16x8 __attribute__((ext_vector_type(8)));
typedef float  f32x4  __attribute__((ext_vector_type(4)));

#define MFMA(a, b, c) __builtin_amdgcn_mfma_f32_16x16x32_bf16((a), (b), (c), 0, 0, 0)

// ---------------- prep kernels ----------------

__global__ void conv_w_kernel(const float* __restrict__ Wxh,
                              const float* __restrict__ Whh,
                              bf16_t* __restrict__ Wc) {
  const int n = blockIdx.y;
  const int k = blockIdx.x * 256 + threadIdx.x;
  const int g = n & 3, j = n >> 2;
  float v = (k < NIN) ? Wxh[(size_t)(g * NH + j) * NIN + k]
                      : Whh[(size_t)(g * NH + j) * NH + (k - NIN)];
  Wc[(size_t)n * KK + k] = (bf16_t)v;
}

__global__ void conv_f2b_kernel(const float* __restrict__ src,
                                bf16_t* __restrict__ dst, int n4) {
  int i = blockIdx.x * 256 + threadIdx.x;
  if (i < n4) {
    float4 v = ((const float4*)src)[i];
    dst[i * 4 + 0] = (bf16_t)v.x;
    dst[i * 4 + 1] = (bf16_t)v.y;
    dst[i * 4 + 2] = (bf16_t)v.z;
    dst[i * 4 + 3] = (bf16_t)v.w;
  }
}

__global__ void prep_bias_kernel(const float* __restrict__ bxh,
                                 const float* __restrict__ bhh,
                                 float* __restrict__ bsum4) {
  int n = blockIdx.x * 256 + threadIdx.x;  // 0..4095
  int g = n & 3, j = n >> 2;
  bsum4[n] = bxh[g * NH + j] + bhh[g * NH + j];
}

// ---------------- fused per-step kernel ----------------

__global__ __launch_bounds__(512, 2) void fused_step(
    int t,
    const bf16_t* __restrict__ x_bf,    // [TT][BB][NIN]
    const bf16_t* __restrict__ Wc,      // [G4][KK] gate-interleaved rows
    const float*  __restrict__ bsum4,   // [G4] gate-interleaved
    const bf16_t* __restrict__ h_cur,   // [BB][NH] = h_{t-1}
    bf16_t*       __restrict__ h_next,  // [BB][NH] = h_t
    float*        __restrict__ c,       // [BB][NH]
    const bf16_t* __restrict__ WoutB,   // [NIN][NH]
    const float*  __restrict__ bout,    // [NIN]
    float*        __restrict__ logits_w,// [BB][NIN] write (step t-1)
    const float*  __restrict__ logits_r,// [BB][NIN] read  (step t-2)
    float*        __restrict__ out)     // [TT][BB][NIN]
{
  const int blk  = blockIdx.x;
  const int tid  = threadIdx.x;
  const int lane = tid & 63;
  const int wv   = tid >> 6;            // 0..7
  const int l16  = lane & 15;
  const int lq   = lane >> 4;

  __shared__ float gs[4 * 64 * 36];     // 4 K-partial regions, row stride 36

  if (t < TT) {
    // ---- Stage A: gates GEMM + cell update ----
    const int mb    = (blk & 1) * 64;
    const int ns    = blk >> 1;         // 0..127 -> 8 hidden units each
    const int nbase = ns * 32;
    const int wm = wv & 1;
    const int wk = wv >> 1;             // K-quarter 0..3
    const int m0 = mb + wm * 32;

    const bf16_t* ax  = x_bf + (size_t)t * BB * NIN + (size_t)(m0 + l16) * NIN + lq * 8;
    const bf16_t* ah  = h_cur + (size_t)(m0 + l16) * NH + lq * 8;
    const bf16_t* b0p = Wc + (size_t)(nbase + l16) * KK + lq * 8;
    const bf16_t* b1p = b0p + (size_t)16 * KK;

    f32x4 a00 = {0,0,0,0}, a01 = {0,0,0,0}, a10 = {0,0,0,0}, a11 = {0,0,0,0};

    // x part: 2 K-chunks of 32 per wave
    const int xo = wk * 64;
#pragma unroll
    for (int i = 0; i < 2; ++i) {
      const int off = xo + i * 32;
      bf16x8 r0 = *(const bf16x8*)(ax + off);
      bf16x8 r1 = *(const bf16x8*)(ax + 16 * NIN + off);
      bf16x8 b0 = *(const bf16x8*)(b0p + off);
      bf16x8 b1 = *(const bf16x8*)(b1p + off);
      a00 = MFMA(r0, b0, a00); a01 = MFMA(r0, b1, a01);
      a10 = MFMA(r1, b0, a10); a11 = MFMA(r1, b1, a11);
    }
    // h part: 8 K-chunks of 32 per wave
    const int ho = wk * 256;
#pragma unroll
    for (int i = 0; i < 8; ++i) {
      const int off = ho + i * 32;
      bf16x8 r0 = *(const bf16x8*)(ah + off);
      bf16x8 r1 = *(const bf16x8*)(ah + 16 * NH + off);
      bf16x8 b0 = *(const bf16x8*)(b0p + NIN + off);
      bf16x8 b1 = *(const bf16x8*)(b1p + NIN + off);
      a00 = MFMA(r0, b0, a00); a01 = MFMA(r0, b1, a01);
      a10 = MFMA(r1, b0, a10); a11 = MFMA(r1, b1, a11);
    }

    // D layout: col = lane&15, row = lq*4 + r
    float* gr = gs + wk * (64 * 36);
#pragma unroll
    for (int r = 0; r < 4; ++r) {
      const int rr = wm * 32 + lq * 4 + r;
      gr[rr * 36 + l16]             = a00[r];
      gr[rr * 36 + 16 + l16]        = a01[r];
      gr[(rr + 16) * 36 + l16]      = a10[r];
      gr[(rr + 16) * 36 + 16 + l16] = a11[r];
    }
    __syncthreads();

    // cell update: one (batch,hidden) pair per thread
    const int b_l = tid >> 3;           // 0..63
    const int jl  = tid & 7;
    const int j   = ns * 8 + jl;        // global hidden idx
    const float4 g0 = *(const float4*)&gs[0 * 64 * 36 + b_l * 36 + jl * 4];
    const float4 g1 = *(const float4*)&gs[1 * 64 * 36 + b_l * 36 + jl * 4];
    const float4 g2 = *(const float4*)&gs[2 * 64 * 36 + b_l * 36 + jl * 4];
    const float4 g3 = *(const float4*)&gs[3 * 64 * 36 + b_l * 36 + jl * 4];
    const float4 bs = ((const float4*)bsum4)[j];
    const float gi = g0.x + g1.x + g2.x + g3.x + bs.x;
    const float gf = g0.y + g1.y + g2.y + g3.y + bs.y;
    const float gg = g0.z + g1.z + g2.z + g3.z + bs.z;
    const float go = g0.w + g1.w + g2.w + g3.w + bs.w;
    const float si = 1.f / (1.f + __expf(-gi));
    const float sf = 1.f / (1.f + __expf(-gf));
    const float so = 1.f / (1.f + __expf(-go));
    const size_t idx = (size_t)(mb + b_l) * NH + j;
    const float cn = sf * c[idx] + si * tanhf(gg);
    c[idx] = cn;
    h_next[idx] = (bf16_t)(so * tanhf(cn));
  }

  if (blk < 16) {
    // ---- Stage B: logits for step t-1 (one 16x16 tile per wave) ----
    if (t >= 1 && t <= TT) {
      const int gw  = blk * 8 + wv;     // 0..127
      const int bm0 = (gw >> 4) * 16;
      const int bn0 = (gw & 15) * 16;
      const bf16_t* ap = h_cur + (size_t)(bm0 + l16) * NH + lq * 8;
      const bf16_t* bp = WoutB + (size_t)(bn0 + l16) * NH + lq * 8;
      f32x4 acc = {0,0,0,0};
#pragma unroll 8
      for (int kk = 0; kk < 32; ++kk) {
        bf16x8 a = *(const bf16x8*)(ap + kk * 32);
        bf16x8 b = *(const bf16x8*)(bp + kk * 32);
        acc = MFMA(a, b, acc);
      }
      const float bo = bout[bn0 + l16];
#pragma unroll
      for (int r = 0; r < 4; ++r)
        logits_w[(size_t)(bm0 + lq * 4 + r) * NIN + bn0 + l16] = acc[r] + bo;
    }
  } else if (blk < 32) {
    // ---- Stage C: log_softmax(logits_{t-2}), one row per wave ----
    if (t >= 2) {
      const int rr = (blk - 16) * 8 + wv;      // 0..127
      float4 v = ((const float4*)(logits_r + (size_t)rr * NIN))[lane];
      float m = fmaxf(fmaxf(v.x, v.y), fmaxf(v.z, v.w));
#pragma unroll
      for (int off = 32; off > 0; off >>= 1) m = fmaxf(m, __shfl_xor(m, off));
      float s = __expf(v.x - m) + __expf(v.y - m) + __expf(v.z - m) + __expf(v.w - m);
#pragma unroll
      for (int off = 32; off > 0; off >>= 1) s += __shfl_xor(s, off);
      const float lse = m + logf(s);
      float4 o = make_float4(v.x - lse, v.y - lse, v.z - lse, v.w - lse);
      ((float4*)(out + (size_t)(t - 2) * BB * NIN + (size_t)rr * NIN))[lane] = o;
    }
  }
}

// ---------------- launcher ----------------

extern "C" void kernel_launch(void* const* d_in, const int* in_sizes, int n_in,
                              void* d_out, int out_size, void* d_ws, size_t ws_size,
                              hipStream_t stream) {
  const float* inp  = (const float*)d_in[0];
  const float* Wxh  = (const float*)d_in[1];
  const float* bxh  = (const float*)d_in[2];
  const float* Whh  = (const float*)d_in[3];
  const float* bhh  = (const float*)d_in[4];
  const float* Wout = (const float*)d_in[5];
  const float* bout = (const float*)d_in[6];
  float* out = (float*)d_out;

  // workspace carve (~46 MB)
  char* p = (char*)d_ws;
  bf16_t* Wc    = (bf16_t*)p; p += (size_t)G4 * KK * 2;        // 10.49 MB
  bf16_t* x_bf  = (bf16_t*)p; p += (size_t)TT * BB * NIN * 2;  // 33.55 MB
  bf16_t* WoutB = (bf16_t*)p; p += (size_t)NIN * NH * 2;       // 0.52 MB
  bf16_t* h0    = (bf16_t*)p; p += (size_t)BB * NH * 2;
  bf16_t* h1    = (bf16_t*)p; p += (size_t)BB * NH * 2;
  float*  cbuf  = (float*)p;  p += (size_t)BB * NH * 4;
  float*  bsum4 = (float*)p;  p += (size_t)G4 * 4;
  float*  lg0   = (float*)p;  p += (size_t)BB * NIN * 4;
  float*  lg1   = (float*)p;  p += (size_t)BB * NIN * 4;

  conv_w_kernel<<<dim3(KK / 256, G4), 256, 0, stream>>>(Wxh, Whh, Wc);
  conv_f2b_kernel<<<(TT * BB * NIN / 4 + 255) / 256, 256, 0, stream>>>(
      inp, x_bf, TT * BB * NIN / 4);
  conv_f2b_kernel<<<(NIN * NH / 4 + 255) / 256, 256, 0, stream>>>(
      Wout, WoutB, NIN * NH / 4);
  prep_bias_kernel<<<G4 / 256, 256, 0, stream>>>(bxh, bhh, bsum4);
  hipMemsetAsync(h0, 0, (size_t)BB * NH * 2, stream);
  hipMemsetAsync(cbuf, 0, (size_t)BB * NH * 4, stream);

  bf16_t* hb[2] = {h0, h1};
  float*  lg[2] = {lg0, lg1};
  for (int t = 0; t < TT + 2; ++t) {
    fused_step<<<256, 512, 0, stream>>>(
        t, x_bf, Wc, bsum4,
        hb[t & 1], hb[(t + 1) & 1], cbuf,
        WoutB, bout,
        lg[t & 1],        // write: logits for step t-1
        lg[(t + 1) & 1],  // read:  logits for step t-2
        out);
  }
}